// Round 7
// baseline (3688.942 us; speedup 1.0000x reference)
//
#include <hip/hip_runtime.h>
#include <hip/hip_bf16.h>
#include <cmath>

typedef unsigned int u32;
typedef unsigned short u16;
typedef unsigned long long u64;
typedef _Float16 f16;
typedef f16 h2 __attribute__((ext_vector_type(2)));
typedef f16 h8 __attribute__((ext_vector_type(8)));
typedef short bf16x8 __attribute__((ext_vector_type(8)));
typedef float f32x4 __attribute__((ext_vector_type(4)));
typedef u16 u16x4 __attribute__((ext_vector_type(4)));

// ---------- sizes ----------
#define Bn 64
#define Tn 1024
#define IDIM 80
#define Hn 256
#define G3 768           // 3*H
#define STOK 5
#define SDIM 128
#define MROWS (Bn*Tn)    // 65536
#define NS 8             // ring slots
#define CH 16            // steps per chunk
#define NCH (Tn/CH)      // 64 chunks

#define AGT __HIP_MEMORY_SCOPE_AGENT

// ---------- helpers ----------
__device__ __forceinline__ float bf2f(u16 v) { return __uint_as_float(((u32)v) << 16); }
__device__ __forceinline__ u16 f2bf(float f) {
  u32 x = __float_as_uint(f);
  return (u16)((x + 0x7FFFu + ((x >> 16) & 1u)) >> 16);   // RNE
}
__device__ __forceinline__ u16 f2h_bits(float f) {
  union { f16 h; u16 u; } cv;
  cv.h = (f16)f;
  return cv.u;
}
__device__ __forceinline__ float fdot2f(h2 a, h2 b, float c) {
#if __has_builtin(__builtin_amdgcn_fdot2)
  return __builtin_amdgcn_fdot2(a, b, c, false);
#else
  return c + (float)a[0] * (float)b[0] + (float)a[1] * (float)b[1];
#endif
}
__device__ __forceinline__ float frcp(float x) {
#if __has_builtin(__builtin_amdgcn_rcpf)
  return __builtin_amdgcn_rcpf(x);
#else
  return 1.f / x;
#endif
}
__device__ __forceinline__ float fsig(float x) { return frcp(1.f + __expf(-x)); }
__device__ __forceinline__ float ftanh(float x) { return 1.f - 2.f * frcp(1.f + __expf(2.f * x)); }
__device__ __forceinline__ float qsum(float v) {
  v += __int_as_float(__builtin_amdgcn_mov_dpp(__float_as_int(v), 0xB1, 0xF, 0xF, true)); // xor 1
  v += __int_as_float(__builtin_amdgcn_mov_dpp(__float_as_int(v), 0x4E, 0xF, 0xF, true)); // xor 2
  return v;
}
#define W2(x) __builtin_bit_cast(h2, (x))

// 16 dot2s for one k-sub-slice i against 4 row-accumulators (R3 wv layout)
#define DOT16(i, hv)                                                     \
  {                                                                      \
    h2 p0 = __builtin_shufflevector(hv, hv, 0, 1);                       \
    h2 p1 = __builtin_shufflevector(hv, hv, 2, 3);                       \
    h2 p2 = __builtin_shufflevector(hv, hv, 4, 5);                       \
    h2 p3 = __builtin_shufflevector(hv, hv, 6, 7);                       \
    a0 = fdot2f(W2(wv[(i)*4 + 0]), p0, a0);                              \
    a0 = fdot2f(W2(wv[(i)*4 + 1]), p1, a0);                              \
    a0 = fdot2f(W2(wv[(i)*4 + 2]), p2, a0);                              \
    a0 = fdot2f(W2(wv[(i)*4 + 3]), p3, a0);                              \
    a1 = fdot2f(W2(wv[32 + (i)*4 + 0]), p0, a1);                         \
    a1 = fdot2f(W2(wv[32 + (i)*4 + 1]), p1, a1);                         \
    a1 = fdot2f(W2(wv[32 + (i)*4 + 2]), p2, a1);                         \
    a1 = fdot2f(W2(wv[32 + (i)*4 + 3]), p3, a1);                         \
    a2 = fdot2f(W2(wv[64 + (i)*4 + 0]), p0, a2);                         \
    a2 = fdot2f(W2(wv[64 + (i)*4 + 1]), p1, a2);                         \
    a2 = fdot2f(W2(wv[64 + (i)*4 + 2]), p2, a2);                         \
    a2 = fdot2f(W2(wv[64 + (i)*4 + 3]), p3, a2);                         \
    a3 = fdot2f(W2(wv[96 + (i)*4 + 0]), p0, a3);                         \
    a3 = fdot2f(W2(wv[96 + (i)*4 + 1]), p1, a3);                         \
    a3 = fdot2f(W2(wv[96 + (i)*4 + 2]), p2, a3);                         \
    a3 = fdot2f(W2(wv[96 + (i)*4 + 3]), p3, a3);                         \
  }

// LDS-only barrier: raw s_barrier so in-flight global ops survive.
__device__ __forceinline__ void lds_barrier() {
  asm volatile("s_waitcnt lgkmcnt(0)" ::: "memory");
  __builtin_amdgcn_sched_barrier(0);
  __builtin_amdgcn_s_barrier();
  __builtin_amdgcn_sched_barrier(0);
}

__device__ __forceinline__ void spin_ge(int* p, int target) {
  while (__hip_atomic_load(p, __ATOMIC_ACQUIRE, AGT) < target)
    __builtin_amdgcn_s_sleep(4);
}

// ---------- conversion / prep kernels ----------
__global__ void k_cvt_bf16(const float* __restrict__ in, u16* __restrict__ out, int n) {
  int i = blockIdx.x * blockDim.x + threadIdx.x;
  int st = gridDim.x * blockDim.x;
  for (; i < n; i += st) out[i] = f2bf(in[i]);
}

// Pack W[768][256] f32 -> per-thread quad-sliced f16 pairs (R3 layout):
// out u32 idx = tau*128 + s*32 + i*4 + p  <=  W[(tau>>2)+192s][64*(tau&3)+8i+2p], pair
__global__ void k_prep_whh(const float* __restrict__ W, u32* __restrict__ out) {
  int idx = blockIdx.x * 256 + threadIdx.x;
  if (idx >= G3 * 128) return;
  int tau = idx >> 7, rest = idx & 127;
  int s = rest >> 5, i2 = (rest >> 2) & 7, p = rest & 3;
  int r = (tau >> 2) + 192 * s;
  int c = 64 * (tau & 3) + 8 * i2 + 2 * p;
  union { f16 h; u16 u; } a, b;
  a.h = (f16)W[r * Hn + c];
  b.h = (f16)W[r * Hn + c + 1];
  out[idx] = ((u32)b.u << 16) | (u32)a.u;
}

__global__ void k_init(int* __restrict__ flags) {
  if (threadIdx.x < 256) flags[threadIdx.x] = 0;
}

// ---------- k/v projection ----------
__global__ __launch_bounds__(256) void k_kv(const float* __restrict__ st,
                                            const float* __restrict__ kw,
                                            const float* __restrict__ vw,
                                            const float* __restrict__ inb,
                                            float* __restrict__ kv) {
  int e = threadIdx.x;
  for (int s = 0; s < STOK; ++s) {
    float ak = inb[Hn + e], av = inb[2 * Hn + e];
    for (int d = 0; d < SDIM; ++d) {
      float x = st[s * SDIM + d];
      ak += x * kw[e * SDIM + d];
      av += x * vw[e * SDIM + d];
    }
    kv[s * Hn + e] = ak;
    kv[STOK * Hn + s * Hn + e] = av;
  }
}

// ---------- MFMA GEMM: C = scale*(A @ B^T + bias) ----------
// MODE 0: f32 out [M][N]; 1: bf16 out [M][N]; 2: bf16 out TRANSPOSED [B][N][T]
template <int MODE>
__global__ __launch_bounds__(256) void k_gemm_bt(const u16* __restrict__ A,
                                                 const u16* __restrict__ B,
                                                 const float* __restrict__ bias,
                                                 float scale, void* __restrict__ Cout,
                                                 int M, int N, int K) {
  constexpr int BM = 128, BN = 128, BK = 32, LDT = 40;
  __shared__ __align__(16) u16 As[BM * LDT];
  __shared__ __align__(16) u16 Bs[BN * LDT];
  const int tid = threadIdx.x;
  const int bm0 = blockIdx.x * BM;
  const int bn0 = blockIdx.y * BN;
  const int lane = tid & 63;
  const int wave = tid >> 6;
  const int wm = (wave & 1) * 64;
  const int wn = (wave >> 1) * 64;
  const int lr = lane & 15;
  const int kg = lane >> 4;
  const int srow = tid >> 1, sch = tid & 1;

  f32x4 acc[4][4] = {};

  for (int k0 = 0; k0 < K; k0 += BK) {
    {
      const u16* gp = A + (size_t)(bm0 + srow) * K + k0 + sch * 16;
      u16* lp = &As[srow * LDT + sch * 16];
      if (k0 + BK <= K) {
        *(uint4*)lp = *(const uint4*)gp;
        *(uint4*)(lp + 8) = *(const uint4*)(gp + 8);
      } else {
        for (int i = 0; i < 16; ++i) {
          int k = k0 + sch * 16 + i;
          lp[i] = (k < K) ? gp[i] : (u16)0;
        }
      }
    }
    {
      const u16* gp = B + (size_t)(bn0 + srow) * K + k0 + sch * 16;
      u16* lp = &Bs[srow * LDT + sch * 16];
      if (k0 + BK <= K) {
        *(uint4*)lp = *(const uint4*)gp;
        *(uint4*)(lp + 8) = *(const uint4*)(gp + 8);
      } else {
        for (int i = 0; i < 16; ++i) {
          int k = k0 + sch * 16 + i;
          lp[i] = (k < K) ? gp[i] : (u16)0;
        }
      }
    }
    __syncthreads();

    bf16x8 af[4], bfr[4];
#pragma unroll
    for (int mi = 0; mi < 4; ++mi)
      af[mi] = *(const bf16x8*)&As[(wm + mi * 16 + lr) * LDT + kg * 8];
#pragma unroll
    for (int ni = 0; ni < 4; ++ni)
      bfr[ni] = *(const bf16x8*)&Bs[(wn + ni * 16 + lr) * LDT + kg * 8];
#pragma unroll
    for (int mi = 0; mi < 4; ++mi)
#pragma unroll
      for (int ni = 0; ni < 4; ++ni)
        acc[mi][ni] = __builtin_amdgcn_mfma_f32_16x16x32_bf16(af[mi], bfr[ni], acc[mi][ni], 0, 0, 0);
    __syncthreads();
  }

  // epilogue: D mapping col=lane&15, row=(lane>>4)*4+reg  [m89/m91 verified]
#pragma unroll
  for (int mi = 0; mi < 4; ++mi)
#pragma unroll
    for (int ni = 0; ni < 4; ++ni) {
      int m0 = bm0 + wm + mi * 16 + kg * 4;
      int col = bn0 + wn + ni * 16 + lr;
      float bv = bias ? bias[col] : 0.f;
      if (MODE == 2) {
        int bidx = m0 >> 10, t0 = m0 & 1023;
        u16x4 pk;
#pragma unroll
        for (int r = 0; r < 4; ++r) pk[r] = f2bf((acc[mi][ni][r] + bv) * scale);
        *(u16x4*)((u16*)Cout + (size_t)bidx * N * Tn + (size_t)col * Tn + t0) = pk;
      } else {
#pragma unroll
        for (int r = 0; r < 4; ++r) {
          float v = (acc[mi][ni][r] + bv) * scale;
          if (MODE == 1)
            ((u16*)Cout)[(size_t)(m0 + r) * N + col] = f2bf(v);
          else
            ((float*)Cout)[(size_t)(m0 + r) * N + col] = v;
        }
      }
    }
}

// ---------- fused pipelined GRU0 -> xg1-chaser -> GRU1 ----------
// 192 blocks x 768 thr. role = blockIdx>>6 (0: GRU layer0, 1: chaser, 2: GRU layer1),
// b = blockIdx&63. All roles hold one 768x256 f16 weight matrix register-resident
// (R3 quad-slice layout): role0 Whh0, role1 Wih1, role2 Whh1.
// role0: scans xgT0, publishes o0 16-step chunks to o0ring (F16 encoding — the
//        chaser consumes them as f16 against f16 weight frags; R6 bug was bf16 here).
// role1: waits prog0, computes xg1 chunk = Wih1 @ o0 + bih1, publishes xg1ring (bf16).
// role2: waits prog1, scans, writes o1 [B][T][256] (bf16 for the MFMA q-GEMM).
// Deadlock-free: role0 only backpressures on chaser (8-slot ring, chaser has 4x slack).
__global__ void __launch_bounds__(768)
__attribute__((amdgpu_waves_per_eu(3, 3)))
k_pipe(const u32* __restrict__ Wh0p, const u32* __restrict__ Wh1p,
       const u32* __restrict__ Wi1p,
       const float* __restrict__ bhh0, const float* __restrict__ bhh1,
       const float* __restrict__ bih1,
       const u16* __restrict__ xgT0,   // [B][768][T]
       u16* __restrict__ o1,           // [B][T][256]
       u16* __restrict__ o0ring,       // [B][NS][16][256]  (f16!)
       u16* __restrict__ xg1ring,      // [B][NS][768][16]  (bf16)
       int* __restrict__ flags) {
  const int tid = threadIdx.x;
  const int role = blockIdx.x >> 6;
  const int b = blockIdx.x & 63;
  const int q = tid & 3;
  const int r0 = tid >> 2;
  __shared__ __align__(16) f16 hsh[Hn];        // quarter-interleaved h
  __shared__ float ght[G3];
  __shared__ __align__(16) u16 xst[CH * G3];   // x stash [u][j] (transposed: conflict-free gate reads)
  __shared__ __align__(16) u16 otile[CH * Hn]; // GRU: h chunk [u][k]; chaser: o0 tile [t][k]

  int* prog0 = flags;
  int* cons0 = flags + 64;
  int* prog1 = flags + 128;
  int* cons1 = flags + 192;

  // weights -> registers, pinned
  const u32* Wp = (role == 0) ? Wh0p : (role == 1) ? Wi1p : Wh1p;
  u32 wv[128];
  {
    const uint4* wp = (const uint4*)(Wp + (size_t)tid * 128);
#pragma unroll
    for (int i = 0; i < 32; ++i) ((uint4*)wv)[i] = wp[i];
  }
#pragma unroll
  for (int i = 0; i < 128; ++i) asm volatile("" : "+v"(wv[i]));

  if (role == 1) {
    // ================= chaser =================
    const float bi = bih1[r0 + 192 * q];
    for (int sc = 0; sc < NCH; ++sc) {
      if (tid == 0) {
        spin_ge(&prog0[b], sc + 1);
        if (sc >= NS) spin_ge(&cons1[b], sc - NS + 1);
      }
      lds_barrier();
      if (tid < 512) {
        const u16* src = o0ring + (size_t)(b * NS + (sc & (NS - 1))) * (CH * Hn)
                         + (tid >> 5) * Hn + (tid & 31) * 8;
        u64 lo = __hip_atomic_load((const u64*)src, __ATOMIC_RELAXED, AGT);
        u64 hi = __hip_atomic_load((const u64*)(src + 4), __ATOMIC_RELAXED, AGT);
        uint4 v;
        v.x = (u32)lo; v.y = (u32)(lo >> 32); v.z = (u32)hi; v.w = (u32)(hi >> 32);
        *(uint4*)&otile[(tid >> 5) * Hn + (tid & 31) * 8] = v;
      }
      lds_barrier();
      u32 pk[8];
#pragma unroll
      for (int t = 0; t < CH; ++t) {
        float a0 = 0.f, a1 = 0.f, a2 = 0.f, a3 = 0.f;
#pragma unroll
        for (int i = 0; i < 8; ++i) {
          h8 hv = *(const h8*)&otile[t * Hn + q * 64 + i * 8];   // f16 payload
          DOT16(i, hv);
        }
        a0 = qsum(a0); a1 = qsum(a1); a2 = qsum(a2); a3 = qsum(a3);
        float sel = (q == 0) ? a0 : (q == 1) ? a1 : (q == 2) ? a2 : a3;
        u16 bv = f2bf(sel + bi);
        if ((t & 1) == 0) pk[t >> 1] = bv;
        else pk[t >> 1] |= ((u32)bv) << 16;
      }
      {
        u16* dst = xg1ring + ((size_t)(b * NS + (sc & (NS - 1))) * G3 + (r0 + 192 * q)) * CH;
#pragma unroll
        for (int k2 = 0; k2 < 4; ++k2) {
          u64 v = (u64)pk[2 * k2] | ((u64)pk[2 * k2 + 1] << 32);
          __hip_atomic_store((u64*)dst + k2, v, __ATOMIC_RELAXED, AGT);
        }
      }
      __threadfence();
      lds_barrier();
      if (tid == 0) {
        __hip_atomic_store(&prog1[b], sc + 1, __ATOMIC_RELEASE, AGT);
        __hip_atomic_store(&cons0[b], sc + 1, __ATOMIC_RELAXED, AGT);
      }
    }
    return;
  }

  // ================= GRU (role 0 / role 2) =================
  const float* bhh = (role == 0) ? bhh0 : bhh1;
  float b0 = 0.f, b1 = 0.f, b2 = 0.f;
  int hidx = 0;
  if (tid < Hn) {
    b0 = bhh[tid]; b1 = bhh[tid + Hn]; b2 = bhh[tid + 2 * Hn];
    hidx = (tid & 7) + ((tid >> 3) & 7) * 32 + (tid >> 6) * 8;
  }
  float hreg = 0.f;
  if (tid < 128) ((h2*)hsh)[tid] = h2{(f16)0.f, (f16)0.f};
  const f16* hbase = hsh + q * 8;
  const u16* xrow = xgT0 + (size_t)b * G3 * Tn + (size_t)tid * Tn;
  uint4 xc0 = {}, xc1 = {};
  if (role == 0) { xc0 = *(const uint4*)xrow; xc1 = *(const uint4*)(xrow + 8); }
  __syncthreads();

  for (int sc = 0; sc < NCH; ++sc) {
    if (role == 2) {
      if (tid == 0) spin_ge(&prog1[b], sc + 1);
      lds_barrier();
      const u16* src = xg1ring + ((size_t)(b * NS + (sc & (NS - 1))) * G3 + tid) * CH;
      u64 d0 = __hip_atomic_load((const u64*)src, __ATOMIC_RELAXED, AGT);
      u64 d1 = __hip_atomic_load((const u64*)(src + 4), __ATOMIC_RELAXED, AGT);
      u64 d2 = __hip_atomic_load((const u64*)(src + 8), __ATOMIC_RELAXED, AGT);
      u64 d3 = __hip_atomic_load((const u64*)(src + 12), __ATOMIC_RELAXED, AGT);
      xc0.x = (u32)d0; xc0.y = (u32)(d0 >> 32); xc0.z = (u32)d1; xc0.w = (u32)(d1 >> 32);
      xc1.x = (u32)d2; xc1.y = (u32)(d2 >> 32); xc1.z = (u32)d3; xc1.w = (u32)(d3 >> 32);
    }
    // stash x chunk transposed: xst[u][j]
#pragma unroll
    for (int u = 0; u < CH; ++u) {
      u32 w = (u < 8) ? ((u32*)&xc0)[u >> 1] : ((u32*)&xc1)[(u - 8) >> 1];
      u16 piece = (u & 1) ? (u16)(w >> 16) : (u16)w;
      xst[u * G3 + tid] = piece;
    }
    if (role == 0) {   // prefetch next chunk (plain loads, hidden under 16 steps)
      int scn = (sc + 1 < NCH) ? sc + 1 : sc;
      xc0 = *(const uint4*)(xrow + scn * CH);
      xc1 = *(const uint4*)(xrow + scn * CH + 8);
    }

    for (int u = 0; u < CH; ++u) {
      // dot phase: 8 x (ds_read_b128 + 16 dot2)
      float a0 = 0.f, a1 = 0.f, a2 = 0.f, a3 = 0.f;
#pragma unroll
      for (int i = 0; i < 8; ++i) {
        h8 hv = *(const h8*)(hbase + i * 32);
        DOT16(i, hv);
      }
      a0 = qsum(a0); a1 = qsum(a1); a2 = qsum(a2); a3 = qsum(a3);
      ght[r0 + 192 * q] = (q == 0) ? a0 : (q == 1) ? a1 : (q == 2) ? a2 : a3;
      lds_barrier();
      // gate phase
      if (tid < Hn) {
        float gr = ght[tid] + b0;
        float gz = ght[tid + Hn] + b1;
        float gn = ght[tid + 2 * Hn] + b2;
        float xr = bf2f(xst[u * G3 + tid]);
        float xz = bf2f(xst[u * G3 + tid + Hn]);
        float xn = bf2f(xst[u * G3 + tid + 2 * Hn]);
        float r = fsig(xr + gr);
        float z = fsig(xz + gz);
        float n = ftanh(xn + r * gn);
        hreg = (1.f - z) * n + z * hreg;
        // ring payload is f16 for role 0 (chaser consumes as f16);
        // bf16 for role 2 (o1 feeds the bf16 MFMA q-GEMM).  [R6 bug fix]
        otile[u * Hn + tid] = (role == 0) ? f2h_bits(hreg) : f2bf(hreg);
        hsh[hidx] = (f16)hreg;
      }
      lds_barrier();
    }

    // chunk boundary
    if (role == 0) {
      if (tid == 0 && sc >= NS) spin_ge(&cons0[b], sc - NS + 1);
      lds_barrier();
      if (tid < 512) {
        uint4 v = *(const uint4*)&otile[(tid >> 5) * Hn + (tid & 31) * 8];
        u16* dst = o0ring + (size_t)(b * NS + (sc & (NS - 1))) * (CH * Hn)
                   + (tid >> 5) * Hn + (tid & 31) * 8;
        u64 lo = (u64)v.x | ((u64)v.y << 32);
        u64 hi = (u64)v.z | ((u64)v.w << 32);
        __hip_atomic_store((u64*)dst, lo, __ATOMIC_RELAXED, AGT);
        __hip_atomic_store((u64*)dst + 1, hi, __ATOMIC_RELAXED, AGT);
      }
      __threadfence();
      lds_barrier();
      if (tid == 0)
        __hip_atomic_store(&prog0[b], sc + 1, __ATOMIC_RELEASE, AGT);
    } else {
      if (tid < 512) {
        uint4 v = *(const uint4*)&otile[(tid >> 5) * Hn + (tid & 31) * 8];
        *(uint4*)(o1 + ((size_t)b * Tn + sc * CH + (tid >> 5)) * Hn + (tid & 31) * 8) = v;
      }
      if (tid == 0)
        __hip_atomic_store(&cons1[b], sc + 1, __ATOMIC_RELAXED, AGT);
    }
  }
}

// ---------- attention over 5 style tokens ----------
__global__ __launch_bounds__(256) void k_attn(const u16* __restrict__ q,
                                              const float* __restrict__ kv,
                                              u16* __restrict__ ctx) {
  __shared__ float ks[STOK * Hn], vs[STOK * Hn];
  int tid = threadIdx.x;
  for (int i = tid; i < STOK * Hn; i += 256) {
    ks[i] = kv[i];
    vs[i] = kv[STOK * Hn + i];
  }
  __syncthreads();
  size_t row = (size_t)blockIdx.x * 256 + tid;
  const u16* qr = q + row * Hn;
  u16* cr = ctx + row * Hn;
#pragma unroll
  for (int h = 0; h < 4; ++h) {
    float sc[STOK] = {0.f, 0.f, 0.f, 0.f, 0.f};
    for (int d = 0; d < 64; ++d) {
      float qv = bf2f(qr[h * 64 + d]);
#pragma unroll
      for (int s = 0; s < STOK; ++s) sc[s] += qv * ks[s * Hn + h * 64 + d];
    }
    float m = sc[0];
#pragma unroll
    for (int s = 1; s < STOK; ++s) m = fmaxf(m, sc[s]);
    float p[STOK], sum = 0.f;
#pragma unroll
    for (int s = 0; s < STOK; ++s) { p[s] = __expf(sc[s] - m); sum += p[s]; }
    float inv = 1.f / sum;
    for (int e = 0; e < 64; ++e) {
      float c = 0.f;
#pragma unroll
      for (int s = 0; s < STOK; ++s) c += p[s] * vs[s * Hn + h * 64 + e];
      cr[h * 64 + e] = f2bf(c * inv);
    }
  }
}

// ---------- workspace layout (bytes) ----------
#define WS_XGT0 ((size_t)0)           // [B][768][T] bf16 = 100,663,296
#define WS_O1   ((size_t)100663296)   // [B][T][256] bf16 = 33,554,432
#define WS_FB   ((size_t)134217728)   // feats bf16 = 10,485,760
#define WS_W0   ((size_t)144703488)   // Wih0 bf16 = 122,880
#define WS_QW   ((size_t)144826368)   // q_w bf16 = 131,072
#define WS_OW   ((size_t)144957440)   // out_w bf16 = 131,072
#define WS_H0P  ((size_t)145088512)   // Whh0 prepped = 393,216
#define WS_H1P  ((size_t)145481728)   // Whh1 prepped = 393,216
#define WS_WI1P ((size_t)145874944)   // Wih1 prepped = 393,216
#define WS_KV   ((size_t)146268160)   // k,v f32 = 10,240
#define WS_FLAG ((size_t)146278400)   // 256 ints = 1,024
#define WS_O0R  ((size_t)146280448)   // o0 ring = 4,194,304
#define WS_XG1R ((size_t)150474752)   // xg1 ring = 12,582,912  (ends 163,057,664)
// aliases into the (dead-after-k_pipe) xgT0 region:
#define WS_QB   ((size_t)0)           // q [B*T][256] bf16
#define WS_CTX  ((size_t)33554432)    // ctx [B*T][256] bf16

extern "C" void kernel_launch(void* const* d_in, const int* in_sizes, int n_in,
                              void* d_out, int out_size, void* d_ws, size_t ws_size,
                              hipStream_t stream) {
  const float* feats = (const float*)d_in[0];
  const float* style = (const float*)d_in[1];
  const float* Wih0 = (const float*)d_in[2];
  const float* Whh0 = (const float*)d_in[3];
  const float* bih0 = (const float*)d_in[4];
  const float* bhh0 = (const float*)d_in[5];
  const float* Wih1 = (const float*)d_in[6];
  const float* Whh1 = (const float*)d_in[7];
  const float* bih1 = (const float*)d_in[8];
  const float* bhh1 = (const float*)d_in[9];
  const float* q_w = (const float*)d_in[10];
  const float* k_w = (const float*)d_in[11];
  const float* v_w = (const float*)d_in[12];
  const float* in_b = (const float*)d_in[13];
  const float* out_w = (const float*)d_in[14];
  const float* out_b = (const float*)d_in[15];

  char* ws = (char*)d_ws;
  u16* xgT0 = (u16*)(ws + WS_XGT0);
  u16* o1 = (u16*)(ws + WS_O1);
  u16* fb = (u16*)(ws + WS_FB);
  u16* w0 = (u16*)(ws + WS_W0);
  u16* qw = (u16*)(ws + WS_QW);
  u16* ow = (u16*)(ws + WS_OW);
  u32* h0p = (u32*)(ws + WS_H0P);
  u32* h1p = (u32*)(ws + WS_H1P);
  u32* wi1p = (u32*)(ws + WS_WI1P);
  float* kv = (float*)(ws + WS_KV);
  int* flags = (int*)(ws + WS_FLAG);
  u16* o0ring = (u16*)(ws + WS_O0R);
  u16* xg1ring = (u16*)(ws + WS_XG1R);
  u16* qb = (u16*)(ws + WS_QB);
  u16* ctx = (u16*)(ws + WS_CTX);

  auto cvgrid = [](int n) { int g = (n + 255) / 256; return g > 2048 ? 2048 : g; };

  // conversions / weight prep / flag init
  k_cvt_bf16<<<cvgrid(MROWS * IDIM), 256, 0, stream>>>(feats, fb, MROWS * IDIM);
  k_cvt_bf16<<<cvgrid(G3 * IDIM), 256, 0, stream>>>(Wih0, w0, G3 * IDIM);
  k_cvt_bf16<<<cvgrid(Hn * Hn), 256, 0, stream>>>(q_w, qw, Hn * Hn);
  k_cvt_bf16<<<cvgrid(Hn * Hn), 256, 0, stream>>>(out_w, ow, Hn * Hn);
  k_prep_whh<<<(G3 * 128 + 255) / 256, 256, 0, stream>>>(Whh0, h0p);
  k_prep_whh<<<(G3 * 128 + 255) / 256, 256, 0, stream>>>(Whh1, h1p);
  k_prep_whh<<<(G3 * 128 + 255) / 256, 256, 0, stream>>>(Wih1, wi1p);
  k_init<<<1, 256, 0, stream>>>(flags);
  k_kv<<<1, 256, 0, stream>>>(style, k_w, v_w, in_b, kv);

  dim3 g768(MROWS / 128, G3 / 128);
  dim3 g256(MROWS / 128, Hn / 128);

  // layer-0 input projection (parallel GEMM, transposed output)
  k_gemm_bt<2><<<g768, 256, 0, stream>>>(fb, w0, bih0, 1.f, xgT0, MROWS, G3, IDIM);

  // fused pipelined GRU0 -> chaser -> GRU1
  k_pipe<<<192, G3, 0, stream>>>(h0p, h1p, wi1p, bhh0, bhh1, bih1,
                                 xgT0, o1, o0ring, xg1ring, flags);

  // attention + output projection
  k_gemm_bt<1><<<g256, 256, 0, stream>>>(o1, qw, in_b, 0.125f, qb, MROWS, Hn, Hn);
  k_attn<<<MROWS / 256, 256, 0, stream>>>(qb, kv, ctx);
  k_gemm_bt<0><<<g256, 256, 0, stream>>>(ctx, ow, out_b, 1.f, d_out, MROWS, Hn, Hn);
}

// Round 8
// 2877.899 us; speedup vs baseline: 1.2818x; 1.2818x over previous
//
#include <hip/hip_runtime.h>
#include <hip/hip_bf16.h>
#include <cmath>

typedef unsigned int u32;
typedef unsigned short u16;
typedef _Float16 f16;
typedef f16 h2 __attribute__((ext_vector_type(2)));
typedef f16 h8 __attribute__((ext_vector_type(8)));
typedef short bf16x8 __attribute__((ext_vector_type(8)));
typedef float f32x4 __attribute__((ext_vector_type(4)));
typedef u16 u16x4 __attribute__((ext_vector_type(4)));

// ---------- sizes ----------
#define Bn 64
#define Tn 1024
#define IDIM 80
#define Hn 256
#define G3 768           // 3*H
#define STOK 5
#define SDIM 128
#define MROWS (Bn*Tn)    // 65536
#define CH 8             // steps per x-chunk

// ---------- helpers ----------
__device__ __forceinline__ float bf2f(u16 v) { return __uint_as_float(((u32)v) << 16); }
__device__ __forceinline__ u16 f2bf(float f) {
  u32 x = __float_as_uint(f);
  return (u16)((x + 0x7FFFu + ((x >> 16) & 1u)) >> 16);   // RNE
}
__device__ __forceinline__ float frcp(float x) {
#if __has_builtin(__builtin_amdgcn_rcpf)
  return __builtin_amdgcn_rcpf(x);
#else
  return 1.f / x;
#endif
}
__device__ __forceinline__ float fsig(float x) { return frcp(1.f + __expf(-x)); }
__device__ __forceinline__ float ftanh(float x) { return 1.f - 2.f * frcp(1.f + __expf(2.f * x)); }
// quad (4-lane) sum via DPP quad_perm
__device__ __forceinline__ float qsum(float v) {
  v += __int_as_float(__builtin_amdgcn_mov_dpp(__float_as_int(v), 0xB1, 0xF, 0xF, true)); // xor 1
  v += __int_as_float(__builtin_amdgcn_mov_dpp(__float_as_int(v), 0x4E, 0xF, 0xF, true)); // xor 2
  return v;
}
#define W2(x) __builtin_bit_cast(h2, (x))

// LDS-only barrier: raw s_barrier so in-flight global ops survive.
__device__ __forceinline__ void lds_barrier() {
  asm volatile("s_waitcnt lgkmcnt(0)" ::: "memory");
  __builtin_amdgcn_sched_barrier(0);
  __builtin_amdgcn_s_barrier();
  __builtin_amdgcn_sched_barrier(0);
}

// ---------- conversion kernels ----------
__global__ void k_cvt_bf16(const float* __restrict__ in, u16* __restrict__ out, int n) {
  int i = blockIdx.x * blockDim.x + threadIdx.x;
  int st = gridDim.x * blockDim.x;
  for (; i < n; i += st) out[i] = f2bf(in[i]);
}

// Pack Whh[768][256] f32 -> per-thread quad-sliced f16 pairs (R3 layout):
// out u32 idx = tau*128 + s*32 + i*4 + p
//   = pack( W[(tau>>2)+192s][64*(tau&3)+8i+2p], [.. +1] )
__global__ void k_prep_whh(const float* __restrict__ W, u32* __restrict__ out) {
  int idx = blockIdx.x * 256 + threadIdx.x;
  if (idx >= G3 * 128) return;
  int tau = idx >> 7, rest = idx & 127;
  int s = rest >> 5, i2 = (rest >> 2) & 7, p = rest & 3;
  int r = (tau >> 2) + 192 * s;
  int c = 64 * (tau & 3) + 8 * i2 + 2 * p;
  union { f16 h; u16 u; } a, b;
  a.h = (f16)W[r * Hn + c];
  b.h = (f16)W[r * Hn + c + 1];
  out[idx] = ((u32)b.u << 16) | (u32)a.u;
}

// ---------- k/v projection ----------
__global__ __launch_bounds__(256) void k_kv(const float* __restrict__ st,
                                            const float* __restrict__ kw,
                                            const float* __restrict__ vw,
                                            const float* __restrict__ inb,
                                            float* __restrict__ kv) {
  int e = threadIdx.x;
  for (int s = 0; s < STOK; ++s) {
    float ak = inb[Hn + e], av = inb[2 * Hn + e];
    for (int d = 0; d < SDIM; ++d) {
      float x = st[s * SDIM + d];
      ak += x * kw[e * SDIM + d];
      av += x * vw[e * SDIM + d];
    }
    kv[s * Hn + e] = ak;
    kv[STOK * Hn + s * Hn + e] = av;
  }
}

// ---------- MFMA GEMM: C = scale*(A @ B^T + bias) ----------
// MODE 0: f32 out [M][N]; 1: bf16 out [M][N]; 2: bf16 out TRANSPOSED [B][N][T]
template <int MODE>
__global__ __launch_bounds__(256) void k_gemm_bt(const u16* __restrict__ A,
                                                 const u16* __restrict__ B,
                                                 const float* __restrict__ bias,
                                                 float scale, void* __restrict__ Cout,
                                                 int M, int N, int K) {
  constexpr int BM = 128, BN = 128, BK = 32, LDT = 40;
  __shared__ __align__(16) u16 As[BM * LDT];
  __shared__ __align__(16) u16 Bs[BN * LDT];
  const int tid = threadIdx.x;
  const int bm0 = blockIdx.x * BM;
  const int bn0 = blockIdx.y * BN;
  const int lane = tid & 63;
  const int wave = tid >> 6;
  const int wm = (wave & 1) * 64;
  const int wn = (wave >> 1) * 64;
  const int lr = lane & 15;
  const int kg = lane >> 4;
  const int srow = tid >> 1, sch = tid & 1;

  f32x4 acc[4][4] = {};

  for (int k0 = 0; k0 < K; k0 += BK) {
    {
      const u16* gp = A + (size_t)(bm0 + srow) * K + k0 + sch * 16;
      u16* lp = &As[srow * LDT + sch * 16];
      if (k0 + BK <= K) {
        *(uint4*)lp = *(const uint4*)gp;
        *(uint4*)(lp + 8) = *(const uint4*)(gp + 8);
      } else {
        for (int i = 0; i < 16; ++i) {
          int k = k0 + sch * 16 + i;
          lp[i] = (k < K) ? gp[i] : (u16)0;
        }
      }
    }
    {
      const u16* gp = B + (size_t)(bn0 + srow) * K + k0 + sch * 16;
      u16* lp = &Bs[srow * LDT + sch * 16];
      if (k0 + BK <= K) {
        *(uint4*)lp = *(const uint4*)gp;
        *(uint4*)(lp + 8) = *(const uint4*)(gp + 8);
      } else {
        for (int i = 0; i < 16; ++i) {
          int k = k0 + sch * 16 + i;
          lp[i] = (k < K) ? gp[i] : (u16)0;
        }
      }
    }
    __syncthreads();

    bf16x8 af[4], bfr[4];
#pragma unroll
    for (int mi = 0; mi < 4; ++mi)
      af[mi] = *(const bf16x8*)&As[(wm + mi * 16 + lr) * LDT + kg * 8];
#pragma unroll
    for (int ni = 0; ni < 4; ++ni)
      bfr[ni] = *(const bf16x8*)&Bs[(wn + ni * 16 + lr) * LDT + kg * 8];
#pragma unroll
    for (int mi = 0; mi < 4; ++mi)
#pragma unroll
      for (int ni = 0; ni < 4; ++ni)
        acc[mi][ni] = __builtin_amdgcn_mfma_f32_16x16x32_bf16(af[mi], bfr[ni], acc[mi][ni], 0, 0, 0);
    __syncthreads();
  }

  // epilogue: D mapping col=lane&15, row=(lane>>4)*4+reg  [m89/m91 verified]
#pragma unroll
  for (int mi = 0; mi < 4; ++mi)
#pragma unroll
    for (int ni = 0; ni < 4; ++ni) {
      int m0 = bm0 + wm + mi * 16 + kg * 4;
      int col = bn0 + wn + ni * 16 + lr;
      float bv = bias ? bias[col] : 0.f;
      if (MODE == 2) {
        // transposed store: [B][N][T], 4 consecutive t per lane -> one 8B store
        int bidx = m0 >> 10, t0 = m0 & 1023;
        u16x4 pk;
#pragma unroll
        for (int r = 0; r < 4; ++r) pk[r] = f2bf((acc[mi][ni][r] + bv) * scale);
        *(u16x4*)((u16*)Cout + (size_t)bidx * N * Tn + (size_t)col * Tn + t0) = pk;
      } else {
#pragma unroll
        for (int r = 0; r < 4; ++r) {
          float v = (acc[mi][ni][r] + bv) * scale;
          if (MODE == 1)
            ((u16*)Cout)[(size_t)(m0 + r) * N + col] = f2bf(v);
          else
            ((float*)Cout)[(size_t)(m0 + r) * N + col] = v;
        }
      }
    }
}

// ---------- transpose oT [B][256][T] -> o [B][T][256] (bf16) ----------
__global__ __launch_bounds__(256) void k_transp(const u16* __restrict__ in,
                                                u16* __restrict__ out) {
  __shared__ u16 tile[64][68];
  int t0 = blockIdx.x * 64, j0 = blockIdx.y * 64, b = blockIdx.z;
  int tx = threadIdx.x & 15, ty = threadIdx.x >> 4;
  const u16* ib = in + (size_t)b * Hn * Tn;
  u16* ob = out + (size_t)b * Tn * Hn;
#pragma unroll
  for (int a = 0; a < 4; ++a) {
    int j = ty + a * 16;
    *(u16x4*)&tile[j][tx * 4] = *(const u16x4*)&ib[(size_t)(j0 + j) * Tn + t0 + tx * 4];
  }
  __syncthreads();
#pragma unroll
  for (int a = 0; a < 4; ++a) {
    int t = ty + a * 16;
    u16x4 v;
    v[0] = tile[tx * 4 + 0][t];
    v[1] = tile[tx * 4 + 1][t];
    v[2] = tile[tx * 4 + 2][t];
    v[3] = tile[tx * 4 + 3][t];
    *(u16x4*)&ob[(size_t)(t0 + t) * Hn + j0 + tx * 4] = v;
  }
}

// ---------- GRU scan (packed-f16 FMA core, chunked I/O, raw barriers) ----------
// One workgroup (768 thr = 12 waves) per chain. Thread tau: quad-slice —
// quarter q=tau&3 of k, rows {r0,+192,+384,+576}, r0=tau>>2; weights 128 u32
// register-resident. h in LDS quarter-interleaved (R3 layout).
// Dot core: 128 v_pk_fma_f16 per thread per step (testing full-rate packed-f16
// vs the measured ~4.4cy/instr of v_dot2_f32_f16). 8 h2 accumulators = 16 f16
// slots, 16 sequential products each -> gh error ~2e-4 (safe).
__global__ void __launch_bounds__(768)
__attribute__((amdgpu_waves_per_eu(3, 3)))
k_gru(const u32* __restrict__ Wp,
      const float* __restrict__ bhh,
      const u16* __restrict__ xgT,   // [B][768][T]
      u16* __restrict__ oT) {        // [B][256][T]
  const int tid = threadIdx.x;
  const int b = blockIdx.x;
  const int q = tid & 3;
  const int r0 = tid >> 2;
  __shared__ __align__(16) f16 hsh[Hn];       // quarter-interleaved
  __shared__ float ght[G3];
  __shared__ __align__(16) u16 xst[CH * G3];  // x stash [u][j] (conflict-free gate reads)

  // weights -> registers, pinned
  u32 wv[128];
  {
    const uint4* wp = (const uint4*)(Wp + (size_t)tid * 128);
#pragma unroll
    for (int i = 0; i < 32; ++i) ((uint4*)wv)[i] = wp[i];
  }
#pragma unroll
  for (int i = 0; i < 128; ++i) asm volatile("" : "+v"(wv[i]));

  float b0 = 0.f, b1 = 0.f, b2 = 0.f;
  int hidx = 0;
  if (tid < Hn) {
    b0 = bhh[tid]; b1 = bhh[tid + Hn]; b2 = bhh[tid + 2 * Hn];
    hidx = (tid & 7) + ((tid >> 3) & 7) * 32 + (tid >> 6) * 8;
  }
  float hreg = 0.f;
  if (tid < 128) ((h2*)hsh)[tid] = h2{(f16)0.f, (f16)0.f};

  const u16* xrow = xgT + (size_t)b * G3 * Tn + (size_t)tid * Tn;  // this thread's gate row
  u16* obT = oT + (size_t)b * Hn * Tn + (size_t)tid * Tn;          // gate threads only
  const f16* hbase = hsh + q * 8;

  uint4 xchunk = *(const uint4*)xrow;   // chunk 0 (steps 0..7)
  u32 hw4[4];
  __syncthreads();   // covers hsh init (one-time; drain OK here)

  for (int tc = 0; tc < Tn / CH; ++tc) {
    // stash this chunk transposed [u][j] (consecutive-lane reads in gate phase)
#pragma unroll
    for (int u = 0; u < CH; ++u) {
      u32 w = ((u32*)&xchunk)[u >> 1];
      u16 piece = (u & 1) ? (u16)(w >> 16) : (u16)w;
      xst[u * G3 + tid] = piece;
    }
    // prefetch next chunk (stays in flight across raw barriers)
    int tcn = (tc + 1 < Tn / CH) ? tc + 1 : tc;
    xchunk = *(const uint4*)(xrow + tcn * CH);

#pragma unroll
    for (int u = 0; u < CH; ++u) {
      // ---- dot phase: 8 x (ds_read_b128 broadcast + 16 pk_fma) ----
      h2 aA0 = {}, aA1 = {}, aA2 = {}, aA3 = {};
      h2 aB0 = {}, aB1 = {}, aB2 = {}, aB3 = {};
#pragma unroll
      for (int i = 0; i < 8; ++i) {
        h8 hv = *(const h8*)(hbase + i * 32);
        h2 p0 = __builtin_shufflevector(hv, hv, 0, 1);
        h2 p1 = __builtin_shufflevector(hv, hv, 2, 3);
        h2 p2 = __builtin_shufflevector(hv, hv, 4, 5);
        h2 p3 = __builtin_shufflevector(hv, hv, 6, 7);
        aA0 = __builtin_elementwise_fma(W2(wv[i * 4 + 0]), p0, aA0);
        aB0 = __builtin_elementwise_fma(W2(wv[i * 4 + 1]), p1, aB0);
        aA0 = __builtin_elementwise_fma(W2(wv[i * 4 + 2]), p2, aA0);
        aB0 = __builtin_elementwise_fma(W2(wv[i * 4 + 3]), p3, aB0);
        aA1 = __builtin_elementwise_fma(W2(wv[32 + i * 4 + 0]), p0, aA1);
        aB1 = __builtin_elementwise_fma(W2(wv[32 + i * 4 + 1]), p1, aB1);
        aA1 = __builtin_elementwise_fma(W2(wv[32 + i * 4 + 2]), p2, aA1);
        aB1 = __builtin_elementwise_fma(W2(wv[32 + i * 4 + 3]), p3, aB1);
        aA2 = __builtin_elementwise_fma(W2(wv[64 + i * 4 + 0]), p0, aA2);
        aB2 = __builtin_elementwise_fma(W2(wv[64 + i * 4 + 1]), p1, aB2);
        aA2 = __builtin_elementwise_fma(W2(wv[64 + i * 4 + 2]), p2, aA2);
        aB2 = __builtin_elementwise_fma(W2(wv[64 + i * 4 + 3]), p3, aB2);
        aA3 = __builtin_elementwise_fma(W2(wv[96 + i * 4 + 0]), p0, aA3);
        aB3 = __builtin_elementwise_fma(W2(wv[96 + i * 4 + 1]), p1, aB3);
        aA3 = __builtin_elementwise_fma(W2(wv[96 + i * 4 + 2]), p2, aA3);
        aB3 = __builtin_elementwise_fma(W2(wv[96 + i * 4 + 3]), p3, aB3);
      }
      float a0 = ((float)aA0[0] + (float)aA0[1]) + ((float)aB0[0] + (float)aB0[1]);
      float a1 = ((float)aA1[0] + (float)aA1[1]) + ((float)aB1[0] + (float)aB1[1]);
      float a2 = ((float)aA2[0] + (float)aA2[1]) + ((float)aB2[0] + (float)aB2[1]);
      float a3 = ((float)aA3[0] + (float)aA3[1]) + ((float)aB3[0] + (float)aB3[1]);
      a0 = qsum(a0); a1 = qsum(a1); a2 = qsum(a2); a3 = qsum(a3);
      float sel = (q == 0) ? a0 : (q == 1) ? a1 : (q == 2) ? a2 : a3;
      ght[r0 + 192 * q] = sel;
      lds_barrier();

      // ---- gate phase (waves 0-3) ----
      if (tid < Hn) {
        float gr = ght[tid] + b0;
        float gz = ght[tid + Hn] + b1;
        float gn = ght[tid + 2 * Hn] + b2;
        float xr = bf2f(xst[u * G3 + tid]);
        float xz = bf2f(xst[u * G3 + tid + Hn]);
        float xn = bf2f(xst[u * G3 + tid + 2 * Hn]);
        float r = fsig(xr + gr);
        float z = fsig(xz + gz);
        float n = ftanh(xn + r * gn);
        hreg = (1.f - z) * n + z * hreg;
        u16 hb16 = f2bf(hreg);
        if ((u & 1) == 0) hw4[u >> 1] = hb16;
        else hw4[u >> 1] |= ((u32)hb16) << 16;
        hsh[hidx] = (f16)hreg;
      }
      lds_barrier();
    }

    // one 16B store per 8 steps (in flight across barriers; no drain)
    if (tid < Hn) {
      uint4 s; s.x = hw4[0]; s.y = hw4[1]; s.z = hw4[2]; s.w = hw4[3];
      *(uint4*)(obT + tc * CH) = s;
    }
  }
}

// ---------- attention over 5 style tokens ----------
__global__ __launch_bounds__(256) void k_attn(const u16* __restrict__ q,
                                              const float* __restrict__ kv,
                                              u16* __restrict__ ctx) {
  __shared__ float ks[STOK * Hn], vs[STOK * Hn];
  int tid = threadIdx.x;
  for (int i = tid; i < STOK * Hn; i += 256) {
    ks[i] = kv[i];
    vs[i] = kv[STOK * Hn + i];
  }
  __syncthreads();
  size_t row = (size_t)blockIdx.x * 256 + tid;
  const u16* qr = q + row * Hn;
  u16* cr = ctx + row * Hn;
#pragma unroll
  for (int h = 0; h < 4; ++h) {
    float sc[STOK] = {0.f, 0.f, 0.f, 0.f, 0.f};
    for (int d = 0; d < 64; ++d) {
      float qv = bf2f(qr[h * 64 + d]);
#pragma unroll
      for (int s = 0; s < STOK; ++s) sc[s] += qv * ks[s * Hn + h * 64 + d];
    }
    float m = sc[0];
#pragma unroll
    for (int s = 1; s < STOK; ++s) m = fmaxf(m, sc[s]);
    float p[STOK], sum = 0.f;
#pragma unroll
    for (int s = 0; s < STOK; ++s) { p[s] = __expf(sc[s] - m); sum += p[s]; }
    float inv = 1.f / sum;
    for (int e = 0; e < 64; ++e) {
      float c = 0.f;
#pragma unroll
      for (int s = 0; s < STOK; ++s) c += p[s] * vs[s * Hn + h * 64 + e];
      cr[h * 64 + e] = f2bf(c * inv);
    }
  }
}

// ---------- workspace layout (bytes) ----------
#define WS_XGT  ((size_t)0)                         // xg^T [B][768][T] bf16 = 100,663,296
#define WS_OT   ((size_t)100663296)                 // oT [B][256][T] bf16 = 33,554,432
#define WS_O    ((size_t)134217728)                 // o  [B][T][256] bf16 = 33,554,432
#define WS_FB   ((size_t)167772160)                 // feats bf16 = 10,485,760
#define WS_W0   ((size_t)178257920)                 // Wih0 bf16 = 122,880
#define WS_W1   ((size_t)178380800)                 // Wih1 bf16 = 393,216
#define WS_QW   ((size_t)178774016)                 // q_w bf16 = 131,072
#define WS_OW   ((size_t)178905088)                 // out_w bf16 = 131,072
#define WS_H0   ((size_t)179036160)                 // Whh0 prepped = 393,216
#define WS_H1   ((size_t)179429376)                 // Whh1 prepped = 393,216
#define WS_KV   ((size_t)179822592)                 // k,v f32 = 10,240
// aliases into the (dead-by-then) xgT region:
#define WS_QB   ((size_t)0)                         // q [B*T][256] bf16
#define WS_CTX  ((size_t)33554432)                  // ctx [B*T][256] bf16

extern "C" void kernel_launch(void* const* d_in, const int* in_sizes, int n_in,
                              void* d_out, int out_size, void* d_ws, size_t ws_size,
                              hipStream_t stream) {
  const float* feats = (const float*)d_in[0];
  const float* style = (const float*)d_in[1];
  const float* Wih0 = (const float*)d_in[2];
  const float* Whh0 = (const float*)d_in[3];
  const float* bih0 = (const float*)d_in[4];
  const float* bhh0 = (const float*)d_in[5];
  const float* Wih1 = (const float*)d_in[6];
  const float* Whh1 = (const float*)d_in[7];
  const float* bih1 = (const float*)d_in[8];
  const float* bhh1 = (const float*)d_in[9];
  const float* q_w = (const float*)d_in[10];
  const float* k_w = (const float*)d_in[11];
  const float* v_w = (const float*)d_in[12];
  const float* in_b = (const float*)d_in[13];
  const float* out_w = (const float*)d_in[14];
  const float* out_b = (const float*)d_in[15];

  char* ws = (char*)d_ws;
  u16* xgT = (u16*)(ws + WS_XGT);
  u16* oT = (u16*)(ws + WS_OT);
  u16* o = (u16*)(ws + WS_O);
  u16* fb = (u16*)(ws + WS_FB);
  u16* w0 = (u16*)(ws + WS_W0);
  u16* w1 = (u16*)(ws + WS_W1);
  u16* qw = (u16*)(ws + WS_QW);
  u16* ow = (u16*)(ws + WS_OW);
  u32* h0 = (u32*)(ws + WS_H0);
  u32* h1 = (u32*)(ws + WS_H1);
  float* kv = (float*)(ws + WS_KV);
  u16* qb = (u16*)(ws + WS_QB);
  u16* ctx = (u16*)(ws + WS_CTX);

  auto cvgrid = [](int n) { int g = (n + 255) / 256; return g > 2048 ? 2048 : g; };

  // conversions / weight prep
  k_cvt_bf16<<<cvgrid(MROWS * IDIM), 256, 0, stream>>>(feats, fb, MROWS * IDIM);
  k_cvt_bf16<<<cvgrid(G3 * IDIM), 256, 0, stream>>>(Wih0, w0, G3 * IDIM);
  k_cvt_bf16<<<cvgrid(G3 * Hn), 256, 0, stream>>>(Wih1, w1, G3 * Hn);
  k_cvt_bf16<<<cvgrid(Hn * Hn), 256, 0, stream>>>(q_w, qw, Hn * Hn);
  k_cvt_bf16<<<cvgrid(Hn * Hn), 256, 0, stream>>>(out_w, ow, Hn * Hn);
  k_prep_whh<<<(G3 * 128 + 255) / 256, 256, 0, stream>>>(Whh0, h0);
  k_prep_whh<<<(G3 * 128 + 255) / 256, 256, 0, stream>>>(Whh1, h1);

  k_kv<<<1, 256, 0, stream>>>(style, k_w, v_w, in_b, kv);

  dim3 g768(MROWS / 128, G3 / 128);
  dim3 g256(MROWS / 128, Hn / 128);
  dim3 gtr(Tn / 64, Hn / 64, Bn);

  // layer 0
  k_gemm_bt<2><<<g768, 256, 0, stream>>>(fb, w0, bih0, 1.f, xgT, MROWS, G3, IDIM);
  k_gru<<<Bn, G3, 0, stream>>>(h0, bhh0, xgT, oT);
  k_transp<<<gtr, 256, 0, stream>>>(oT, o);
  // layer 1
  k_gemm_bt<2><<<g768, 256, 0, stream>>>(o, w1, bih1, 1.f, xgT, MROWS, G3, Hn);
  k_gru<<<Bn, G3, 0, stream>>>(h1, bhh1, xgT, oT);
  k_transp<<<gtr, 256, 0, stream>>>(oT, o);
  // attention
  k_gemm_bt<1><<<g256, 256, 0, stream>>>(o, qw, in_b, 0.125f, qb, MROWS, Hn, Hn);
  k_attn<<<MROWS / 256, 256, 0, stream>>>(qb, kv, ctx);
  // output projection
  k_gemm_bt<0><<<g256, 256, 0, stream>>>(ctx, ow, out_b, 1.f, d_out, MROWS, Hn, Hn);
}

// Round 9
// 2501.642 us; speedup vs baseline: 1.4746x; 1.1504x over previous
//
#include <hip/hip_runtime.h>
#include <hip/hip_bf16.h>
#include <cmath>

typedef unsigned int u32;
typedef unsigned short u16;
typedef _Float16 f16;
typedef f16 h2 __attribute__((ext_vector_type(2)));
typedef f16 h8 __attribute__((ext_vector_type(8)));
typedef short bf16x8 __attribute__((ext_vector_type(8)));
typedef float f32x4 __attribute__((ext_vector_type(4)));
typedef u16 u16x4 __attribute__((ext_vector_type(4)));

// ---------- sizes ----------
#define Bn 64
#define Tn 1024
#define IDIM 80
#define Hn 256
#define G3 768           // 3*H
#define STOK 5
#define SDIM 128
#define MROWS (Bn*Tn)    // 65536
#define CH 8             // steps per x-chunk (Tn/CH = 128 chunks; half = 64)

// ---------- helpers ----------
__device__ __forceinline__ float bf2f(u16 v) { return __uint_as_float(((u32)v) << 16); }
__device__ __forceinline__ u16 f2bf(float f) {
  u32 x = __float_as_uint(f);
  return (u16)((x + 0x7FFFu + ((x >> 16) & 1u)) >> 16);   // RNE
}
__device__ __forceinline__ float fdot2f(h2 a, h2 b, float c) {
#if __has_builtin(__builtin_amdgcn_fdot2)
  return __builtin_amdgcn_fdot2(a, b, c, false);
#else
  return c + (float)a[0] * (float)b[0] + (float)a[1] * (float)b[1];
#endif
}
__device__ __forceinline__ float frcp(float x) {
#if __has_builtin(__builtin_amdgcn_rcpf)
  return __builtin_amdgcn_rcpf(x);
#else
  return 1.f / x;
#endif
}
__device__ __forceinline__ float fsig(float x) { return frcp(1.f + __expf(-x)); }
__device__ __forceinline__ float ftanh(float x) { return 1.f - 2.f * frcp(1.f + __expf(2.f * x)); }
__device__ __forceinline__ float qsum(float v) {
  v += __int_as_float(__builtin_amdgcn_mov_dpp(__float_as_int(v), 0xB1, 0xF, 0xF, true)); // xor 1
  v += __int_as_float(__builtin_amdgcn_mov_dpp(__float_as_int(v), 0x4E, 0xF, 0xF, true)); // xor 2
  return v;
}
#define W2(x) __builtin_bit_cast(h2, (x))

// 16 dot2s for one k-sub-slice i against 4 row-accumulators
#define DOT16(i, hv)                                                     \
  {                                                                      \
    h2 p0 = __builtin_shufflevector(hv, hv, 0, 1);                       \
    h2 p1 = __builtin_shufflevector(hv, hv, 2, 3);                       \
    h2 p2 = __builtin_shufflevector(hv, hv, 4, 5);                       \
    h2 p3 = __builtin_shufflevector(hv, hv, 6, 7);                       \
    a0 = fdot2f(W2(wv[(i)*4 + 0]), p0, a0);                              \
    a0 = fdot2f(W2(wv[(i)*4 + 1]), p1, a0);                              \
    a0 = fdot2f(W2(wv[(i)*4 + 2]), p2, a0);                              \
    a0 = fdot2f(W2(wv[(i)*4 + 3]), p3, a0);                              \
    a1 = fdot2f(W2(wv[32 + (i)*4 + 0]), p0, a1);                         \
    a1 = fdot2f(W2(wv[32 + (i)*4 + 1]), p1, a1);                         \
    a1 = fdot2f(W2(wv[32 + (i)*4 + 2]), p2, a1);                         \
    a1 = fdot2f(W2(wv[32 + (i)*4 + 3]), p3, a1);                         \
    a2 = fdot2f(W2(wv[64 + (i)*4 + 0]), p0, a2);                         \
    a2 = fdot2f(W2(wv[64 + (i)*4 + 1]), p1, a2);                         \
    a2 = fdot2f(W2(wv[64 + (i)*4 + 2]), p2, a2);                         \
    a2 = fdot2f(W2(wv[64 + (i)*4 + 3]), p3, a2);                         \
    a3 = fdot2f(W2(wv[96 + (i)*4 + 0]), p0, a3);                         \
    a3 = fdot2f(W2(wv[96 + (i)*4 + 1]), p1, a3);                         \
    a3 = fdot2f(W2(wv[96 + (i)*4 + 2]), p2, a3);                         \
    a3 = fdot2f(W2(wv[96 + (i)*4 + 3]), p3, a3);                         \
  }

// LDS-only barrier: raw s_barrier so in-flight global ops survive.
__device__ __forceinline__ void lds_barrier() {
  asm volatile("s_waitcnt lgkmcnt(0)" ::: "memory");
  __builtin_amdgcn_sched_barrier(0);
  __builtin_amdgcn_s_barrier();
  __builtin_amdgcn_sched_barrier(0);
}

// ---------- conversion / prep ----------
__global__ void k_cvt_bf16(const float* __restrict__ in, u16* __restrict__ out, int n) {
  int i = blockIdx.x * blockDim.x + threadIdx.x;
  int st = gridDim.x * blockDim.x;
  for (; i < n; i += st) out[i] = f2bf(in[i]);
}

// Pack Whh[768][256] f32 -> per-thread quad-sliced f16 pairs.
// BANK-FIX mapping: thread tau's 4 rows are {4*(tau>>2)+s, s=0..3} (interleaved),
// so the gh store lands at ght[tid] (consecutive words, conflict-free) and the
// gate still reads ght[j] == gh[j] naturally.
// out u32 idx = tau*128 + s*32 + i*4 + p <= pack(W[4*(tau>>2)+s][64*(tau&3)+8i+2p], pair)
__global__ void k_prep_whh(const float* __restrict__ W, u32* __restrict__ out) {
  int idx = blockIdx.x * 256 + threadIdx.x;
  if (idx >= G3 * 128) return;
  int tau = idx >> 7, rest = idx & 127;
  int s = rest >> 5, i2 = (rest >> 2) & 7, p = rest & 3;
  int r = 4 * (tau >> 2) + s;
  int c = 64 * (tau & 3) + 8 * i2 + 2 * p;
  union { f16 h; u16 u; } a, b;
  a.h = (f16)W[r * Hn + c];
  b.h = (f16)W[r * Hn + c + 1];
  out[idx] = ((u32)b.u << 16) | (u32)a.u;
}

// ---------- k/v projection ----------
__global__ __launch_bounds__(256) void k_kv(const float* __restrict__ st,
                                            const float* __restrict__ kw,
                                            const float* __restrict__ vw,
                                            const float* __restrict__ inb,
                                            float* __restrict__ kv) {
  int e = threadIdx.x;
  for (int s = 0; s < STOK; ++s) {
    float ak = inb[Hn + e], av = inb[2 * Hn + e];
    for (int d = 0; d < SDIM; ++d) {
      float x = st[s * SDIM + d];
      ak += x * kw[e * SDIM + d];
      av += x * vw[e * SDIM + d];
    }
    kv[s * Hn + e] = ak;
    kv[STOK * Hn + s * Hn + e] = av;
  }
}

// ---------- standalone MFMA GEMM (head/tail): C = scale*(A @ B^T + bias) ----------
// MODE 0: f32 out [M][N]; 1: bf16 out [M][N]; 2: bf16 out TRANSPOSED [B][N][T]
template <int MODE>
__global__ __launch_bounds__(256) void k_gemm_bt(const u16* __restrict__ A,
                                                 const u16* __restrict__ B,
                                                 const float* __restrict__ bias,
                                                 float scale, void* __restrict__ Cout,
                                                 int M, int N, int K) {
  constexpr int BM = 128, BN = 128, BK = 32, LDT = 40;
  __shared__ __align__(16) u16 As[BM * LDT];
  __shared__ __align__(16) u16 Bs[BN * LDT];
  const int tid = threadIdx.x;
  const int bm0 = blockIdx.x * BM;
  const int bn0 = blockIdx.y * BN;
  const int lane = tid & 63;
  const int wave = tid >> 6;
  const int wm = (wave & 1) * 64;
  const int wn = (wave >> 1) * 64;
  const int lr = lane & 15;
  const int kg = lane >> 4;
  const int srow = tid >> 1, sch = tid & 1;

  f32x4 acc[4][4] = {};

  for (int k0 = 0; k0 < K; k0 += BK) {
    {
      const u16* gp = A + (size_t)(bm0 + srow) * K + k0 + sch * 16;
      u16* lp = &As[srow * LDT + sch * 16];
      if (k0 + BK <= K) {
        *(uint4*)lp = *(const uint4*)gp;
        *(uint4*)(lp + 8) = *(const uint4*)(gp + 8);
      } else {
        for (int i = 0; i < 16; ++i) {
          int k = k0 + sch * 16 + i;
          lp[i] = (k < K) ? gp[i] : (u16)0;
        }
      }
    }
    {
      const u16* gp = B + (size_t)(bn0 + srow) * K + k0 + sch * 16;
      u16* lp = &Bs[srow * LDT + sch * 16];
      if (k0 + BK <= K) {
        *(uint4*)lp = *(const uint4*)gp;
        *(uint4*)(lp + 8) = *(const uint4*)(gp + 8);
      } else {
        for (int i = 0; i < 16; ++i) {
          int k = k0 + sch * 16 + i;
          lp[i] = (k < K) ? gp[i] : (u16)0;
        }
      }
    }
    __syncthreads();

    bf16x8 af[4], bfr[4];
#pragma unroll
    for (int mi = 0; mi < 4; ++mi)
      af[mi] = *(const bf16x8*)&As[(wm + mi * 16 + lr) * LDT + kg * 8];
#pragma unroll
    for (int ni = 0; ni < 4; ++ni)
      bfr[ni] = *(const bf16x8*)&Bs[(wn + ni * 16 + lr) * LDT + kg * 8];
#pragma unroll
    for (int mi = 0; mi < 4; ++mi)
#pragma unroll
      for (int ni = 0; ni < 4; ++ni)
        acc[mi][ni] = __builtin_amdgcn_mfma_f32_16x16x32_bf16(af[mi], bfr[ni], acc[mi][ni], 0, 0, 0);
    __syncthreads();
  }

  // epilogue: D mapping col=lane&15, row=(lane>>4)*4+reg  [m89/m91 verified]
#pragma unroll
  for (int mi = 0; mi < 4; ++mi)
#pragma unroll
    for (int ni = 0; ni < 4; ++ni) {
      int m0 = bm0 + wm + mi * 16 + kg * 4;
      int col = bn0 + wn + ni * 16 + lr;
      float bv = bias ? bias[col] : 0.f;
      if (MODE == 2) {
        int bidx = m0 >> 10, t0 = m0 & 1023;
        u16x4 pk;
#pragma unroll
        for (int r = 0; r < 4; ++r) pk[r] = f2bf((acc[mi][ni][r] + bv) * scale);
        *(u16x4*)((u16*)Cout + (size_t)bidx * N * Tn + (size_t)col * Tn + t0) = pk;
      } else {
#pragma unroll
        for (int r = 0; r < 4; ++r) {
          float v = (acc[mi][ni][r] + bv) * scale;
          if (MODE == 1)
            ((u16*)Cout)[(size_t)(m0 + r) * N + col] = f2bf(v);
          else
            ((float*)Cout)[(size_t)(m0 + r) * N + col] = v;
        }
      }
    }
}

// ---------- mega kernel: GRU half-scan (blocks 0..63) + GEMM riders ----------
// gruH: -1 none, else half (0/1) of the T range for this layer's scan.
//   Scan state h persisted in hst[b][256] (f32) between halves.
//   gru writes o in NORMAL layout [B][T][256] (2B/step coalesced stores).
// gemm rider (blocks >= ngru): C = gScale*(gA @ gB^T + gBias), K=256 fixed,
//   M-rows = (b, t in half gmH), 256 m-tiles x (gmN/128) n-tiles.
//   gmMode 2: bf16 transposed out [B][gmN][Tn] (xg1 in-place into xgT);
//   gmMode 1: bf16 normal out [rows][gmN] (qb).
__global__ void __launch_bounds__(768)
__attribute__((amdgpu_waves_per_eu(3, 3)))
k_mega(const u32* __restrict__ Wp, const float* __restrict__ bhh,
       u16* __restrict__ xgT, u16* __restrict__ o, float* __restrict__ hst,
       int gruH,
       const u16* __restrict__ gA, const u16* __restrict__ gB,
       const float* __restrict__ gBias, float gScale,
       u16* __restrict__ gC, int gmMode, int gmH, int gmN) {
  const int ngru = (gruH >= 0) ? 64 : 0;
  const int tid = threadIdx.x;
  __shared__ __align__(16) char ldsu[20608];   // max(gru 15.9KB, gemm 20.5KB)

  if ((int)blockIdx.x < ngru) {
    // ================= GRU role =================
    f16* hsh = (f16*)ldsu;                      // 512 B (quarter-interleaved h)
    float* ght = (float*)(ldsu + 512);          // 3072 B
    u16* xst = (u16*)(ldsu + 512 + 3072);       // 12288 B, [u][j]
    const int b = blockIdx.x;
    const int q = tid & 3;

    u32 wv[128];
    {
      const uint4* wp = (const uint4*)(Wp + (size_t)tid * 128);
#pragma unroll
      for (int i = 0; i < 32; ++i) ((uint4*)wv)[i] = wp[i];
    }
#pragma unroll
    for (int i = 0; i < 128; ++i) asm volatile("" : "+v"(wv[i]));

    float b0 = 0.f, b1 = 0.f, b2 = 0.f;
    int hidx = 0;
    if (tid < Hn) {
      b0 = bhh[tid]; b1 = bhh[tid + Hn]; b2 = bhh[tid + 2 * Hn];
      hidx = (tid & 7) + ((tid >> 3) & 7) * 32 + (tid >> 6) * 8;
    }
    float hreg = 0.f;
    if (gruH > 0 && tid < Hn) hreg = hst[b * Hn + tid];
    if (tid < Hn) hsh[hidx] = (f16)hreg;

    const u16* xrow = xgT + (size_t)b * G3 * Tn + (size_t)tid * Tn;
    u16* ob = o + (size_t)b * Tn * Hn;
    const f16* hbase = hsh + q * 8;
    const int tc0 = gruH * 64, tc1 = tc0 + 64;

    uint4 xchunk = *(const uint4*)(xrow + tc0 * CH);
    __syncthreads();

    for (int tc = tc0; tc < tc1; ++tc) {
      // stash chunk transposed [u][j]
#pragma unroll
      for (int u = 0; u < CH; ++u) {
        u32 w = ((u32*)&xchunk)[u >> 1];
        u16 piece = (u & 1) ? (u16)(w >> 16) : (u16)w;
        xst[u * G3 + tid] = piece;
      }
      int tcn = (tc + 1 < Tn / CH) ? tc + 1 : tc;
      xchunk = *(const uint4*)(xrow + tcn * CH);

#pragma unroll
      for (int u = 0; u < CH; ++u) {
        // dot phase: 8 x (ds_read_b128 broadcast + 16 dot2)
        float a0 = 0.f, a1 = 0.f, a2 = 0.f, a3 = 0.f;
#pragma unroll
        for (int i = 0; i < 8; ++i) {
          h8 hv = *(const h8*)(hbase + i * 32);
          DOT16(i, hv);
        }
        a0 = qsum(a0); a1 = qsum(a1); a2 = qsum(a2); a3 = qsum(a3);
        // rows are 4*(tid>>2)+s => this lane's row = tid; conflict-free store
        ght[tid] = (q == 0) ? a0 : (q == 1) ? a1 : (q == 2) ? a2 : a3;
        lds_barrier();
        // gate phase (waves 0-3)
        if (tid < Hn) {
          float gr = ght[tid] + b0;
          float gz = ght[tid + Hn] + b1;
          float gn = ght[tid + 2 * Hn] + b2;
          float xr = bf2f(xst[u * G3 + tid]);
          float xz = bf2f(xst[u * G3 + tid + Hn]);
          float xn = bf2f(xst[u * G3 + tid + 2 * Hn]);
          float r = fsig(xr + gr);
          float z = fsig(xz + gz);
          float n = ftanh(xn + r * gn);
          hreg = (1.f - z) * n + z * hreg;
          ob[(size_t)(tc * CH + u) * Hn + tid] = f2bf(hreg);
          hsh[hidx] = (f16)hreg;
        }
        lds_barrier();
      }
    }
    if (tid < Hn) hst[b * Hn + tid] = hreg;
    return;
  }

  // ================= GEMM rider =================
  if (gmMode == 0) return;
  constexpr int LDT = 40;
  u16* As = (u16*)ldsu;             // [128*40]
  u16* Bs = (u16*)(ldsu + 10240);   // [128*40]
  const int idx = blockIdx.x - ngru;
  const int mt = idx & 255, nt = idx >> 8;
  const int bm0 = (mt >> 2) * Tn + gmH * 512 + (mt & 3) * 128;
  const int bn0 = nt * 128;
  const int lane = tid & 63;
  const int wave = tid >> 6;
  const int wm = (wave & 1) * 64;
  const int wn = (wave >> 1) * 64;
  const int lr = lane & 15;
  const int kg = lane >> 4;
  const int srow = (tid & 255) >> 1, sch = tid & 1;

  f32x4 acc[4][4] = {};

  for (int k0 = 0; k0 < 256; k0 += 32) {
    if (tid < 256) {
      const u16* gp = gA + (size_t)(bm0 + srow) * 256 + k0 + sch * 16;
      u16* lp = &As[srow * LDT + sch * 16];
      *(uint4*)lp = *(const uint4*)gp;
      *(uint4*)(lp + 8) = *(const uint4*)(gp + 8);
      const u16* gp2 = gB + (size_t)(bn0 + srow) * 256 + k0 + sch * 16;
      u16* lp2 = &Bs[srow * LDT + sch * 16];
      *(uint4*)lp2 = *(const uint4*)gp2;
      *(uint4*)(lp2 + 8) = *(const uint4*)(gp2 + 8);
    }
    __syncthreads();
    if (tid < 256) {
      bf16x8 af[4], bfr[4];
#pragma unroll
      for (int mi = 0; mi < 4; ++mi)
        af[mi] = *(const bf16x8*)&As[(wm + mi * 16 + lr) * LDT + kg * 8];
#pragma unroll
      for (int ni = 0; ni < 4; ++ni)
        bfr[ni] = *(const bf16x8*)&Bs[(wn + ni * 16 + lr) * LDT + kg * 8];
#pragma unroll
      for (int mi = 0; mi < 4; ++mi)
#pragma unroll
        for (int ni = 0; ni < 4; ++ni)
          acc[mi][ni] = __builtin_amdgcn_mfma_f32_16x16x32_bf16(af[mi], bfr[ni], acc[mi][ni], 0, 0, 0);
    }
    __syncthreads();
  }

  if (tid < 256) {
#pragma unroll
    for (int mi = 0; mi < 4; ++mi)
#pragma unroll
      for (int ni = 0; ni < 4; ++ni) {
        int m0 = bm0 + wm + mi * 16 + kg * 4;
        int col = bn0 + wn + ni * 16 + lr;
        float bv = gBias[col];
        if (gmMode == 2) {
          int bidx = m0 >> 10, t0 = m0 & 1023;
          u16x4 pk;
#pragma unroll
          for (int r = 0; r < 4; ++r) pk[r] = f2bf((acc[mi][ni][r] + bv) * gScale);
          *(u16x4*)(gC + (size_t)bidx * gmN * Tn + (size_t)col * Tn + t0) = pk;
        } else {
#pragma unroll
          for (int r = 0; r < 4; ++r)
            gC[(size_t)(m0 + r) * gmN + col] = f2bf((acc[mi][ni][r] + bv) * gScale);
        }
      }
  }
}

// ---------- attention over 5 style tokens ----------
__global__ __launch_bounds__(256) void k_attn(const u16* __restrict__ q,
                                              const float* __restrict__ kv,
                                              u16* __restrict__ ctx) {
  __shared__ float ks[STOK * Hn], vs[STOK * Hn];
  int tid = threadIdx.x;
  for (int i = tid; i < STOK * Hn; i += 256) {
    ks[i] = kv[i];
    vs[i] = kv[STOK * Hn + i];
  }
  __syncthreads();
  size_t row = (size_t)blockIdx.x * 256 + tid;
  const u16* qr = q + row * Hn;
  u16* cr = ctx + row * Hn;
#pragma unroll
  for (int h = 0; h < 4; ++h) {
    float sc[STOK] = {0.f, 0.f, 0.f, 0.f, 0.f};
    for (int d = 0; d < 64; ++d) {
      float qv = bf2f(qr[h * 64 + d]);
#pragma unroll
      for (int s = 0; s < STOK; ++s) sc[s] += qv * ks[s * Hn + h * 64 + d];
    }
    float m = sc[0];
#pragma unroll
    for (int s = 1; s < STOK; ++s) m = fmaxf(m, sc[s]);
    float p[STOK], sum = 0.f;
#pragma unroll
    for (int s = 0; s < STOK; ++s) { p[s] = __expf(sc[s] - m); sum += p[s]; }
    float inv = 1.f / sum;
    for (int e = 0; e < 64; ++e) {
      float c = 0.f;
#pragma unroll
      for (int s = 0; s < STOK; ++s) c += p[s] * vs[s * Hn + h * 64 + e];
      cr[h * 64 + e] = f2bf(c * inv);
    }
  }
}

// ---------- workspace layout (bytes; max 179,832,832 = proven R5 extent) ----------
#define WS_XGT  ((size_t)0)           // [B][768][T] bf16 = 100,663,296 (xg0, then xg1 in-place)
#define WS_O    ((size_t)100663296)   // [B][T][256] bf16 = 33,554,432 (o0, then o1 in-place)
#define WS_QB   ((size_t)134217728)   // q [B*T][256] bf16 = 33,554,432
#define WS_FB   ((size_t)167772160)   // feats bf16 = 10,485,760 (hst aliases after head)
#define WS_W0   ((size_t)178257920)   // Wih0 bf16 = 122,880
#define WS_W1   ((size_t)178380800)   // Wih1 bf16 = 393,216
#define WS_QW   ((size_t)178774016)   // q_w bf16 = 131,072
#define WS_OW   ((size_t)178905088)   // out_w bf16 = 131,072
#define WS_H0P  ((size_t)179036160)   // Whh0 prepped = 393,216
#define WS_H1P  ((size_t)179429376)   // Whh1 prepped = 393,216
#define WS_KV   ((size_t)179822592)   // k,v f32 = 10,240
#define WS_HST  WS_FB                 // h state f32 [64][256] = 65,536 (fb dead after head)
#define WS_CTX  WS_XGT                // ctx [B*T][256] bf16 (xgT dead after D4)

extern "C" void kernel_launch(void* const* d_in, const int* in_sizes, int n_in,
                              void* d_out, int out_size, void* d_ws, size_t ws_size,
                              hipStream_t stream) {
  const float* feats = (const float*)d_in[0];
  const float* style = (const float*)d_in[1];
  const float* Wih0 = (const float*)d_in[2];
  const float* Whh0 = (const float*)d_in[3];
  const float* bih0 = (const float*)d_in[4];
  const float* bhh0 = (const float*)d_in[5];
  const float* Wih1 = (const float*)d_in[6];
  const float* Whh1 = (const float*)d_in[7];
  const float* bih1 = (const float*)d_in[8];
  const float* bhh1 = (const float*)d_in[9];
  const float* q_w = (const float*)d_in[10];
  const float* k_w = (const float*)d_in[11];
  const float* v_w = (const float*)d_in[12];
  const float* in_b = (const float*)d_in[13];
  const float* out_w = (const float*)d_in[14];
  const float* out_b = (const float*)d_in[15];

  char* ws = (char*)d_ws;
  u16* xgT = (u16*)(ws + WS_XGT);
  u16* o = (u16*)(ws + WS_O);
  u16* qb = (u16*)(ws + WS_QB);
  u16* fb = (u16*)(ws + WS_FB);
  u16* w0 = (u16*)(ws + WS_W0);
  u16* w1 = (u16*)(ws + WS_W1);
  u16* qw = (u16*)(ws + WS_QW);
  u16* ow = (u16*)(ws + WS_OW);
  u32* h0p = (u32*)(ws + WS_H0P);
  u32* h1p = (u32*)(ws + WS_H1P);
  float* kv = (float*)(ws + WS_KV);
  float* hst = (float*)(ws + WS_HST);
  u16* ctx = (u16*)(ws + WS_CTX);

  auto cvgrid = [](int n) { int g = (n + 255) / 256; return g > 2048 ? 2048 : g; };

  // ---- head: conversions, weight prep, kv, xg0 GEMM ----
  k_cvt_bf16<<<cvgrid(MROWS * IDIM), 256, 0, stream>>>(feats, fb, MROWS * IDIM);
  k_cvt_bf16<<<cvgrid(G3 * IDIM), 256, 0, stream>>>(Wih0, w0, G3 * IDIM);
  k_cvt_bf16<<<cvgrid(G3 * Hn), 256, 0, stream>>>(Wih1, w1, G3 * Hn);
  k_cvt_bf16<<<cvgrid(Hn * Hn), 256, 0, stream>>>(q_w, qw, Hn * Hn);
  k_cvt_bf16<<<cvgrid(Hn * Hn), 256, 0, stream>>>(out_w, ow, Hn * Hn);
  k_prep_whh<<<(G3 * 128 + 255) / 256, 256, 0, stream>>>(Whh0, h0p);
  k_prep_whh<<<(G3 * 128 + 255) / 256, 256, 0, stream>>>(Whh1, h1p);
  k_kv<<<1, 256, 0, stream>>>(style, k_w, v_w, in_b, kv);

  dim3 g768(MROWS / 128, G3 / 128);
  k_gemm_bt<2><<<g768, 256, 0, stream>>>(fb, w0, bih0, 1.f, xgT, MROWS, G3, IDIM);

  // ---- pipelined halves: gru + co-dispatched GEMM riders ----
  // D1: gru L0 h0
  k_mega<<<64, 768, 0, stream>>>(h0p, bhh0, xgT, o, hst, 0,
                                 nullptr, nullptr, nullptr, 0.f, nullptr, 0, 0, 0);
  // D2: gru L0 h1  |  xg1 GEMM h0 (o@Wih1^T + bih1 -> xgT in-place, t<512)
  k_mega<<<64 + 1536, 768, 0, stream>>>(h0p, bhh0, xgT, o, hst, 1,
                                        o, w1, bih1, 1.f, xgT, 2, 0, G3);
  // D3: gru L1 h0  |  xg1 GEMM h1
  k_mega<<<64 + 1536, 768, 0, stream>>>(h1p, bhh1, xgT, o, hst, 0,
                                        o, w1, bih1, 1.f, xgT, 2, 1, G3);
  // D4: gru L1 h1  |  q GEMM h0 (o@q_w^T + bq)*0.125 -> qb
  k_mega<<<64 + 512, 768, 0, stream>>>(h1p, bhh1, xgT, o, hst, 1,
                                       o, qw, in_b, 0.125f, qb, 1, 0, Hn);
  // D5: q GEMM h1
  k_mega<<<512, 768, 0, stream>>>(h0p, bhh0, xgT, o, hst, -1,
                                  o, qw, in_b, 0.125f, qb, 1, 1, Hn);

  // ---- tail: attention + output projection ----
  k_attn<<<MROWS / 256, 256, 0, stream>>>(qb, kv, ctx);
  dim3 g256t(MROWS / 128, Hn / 128);
  k_gemm_bt<0><<<g256t, 256, 0, stream>>>(ctx, ow, out_b, 1.f, d_out, MROWS, Hn, Hn);
}